// Round 5
// baseline (405.642 us; speedup 1.0000x reference)
//
#include <hip/hip_runtime.h>

// T5Attention on MI355X (gfx950).
// Pipeline: prep (table+convert+transpose) -> qkv_gemm -> attn(+bias write) -> out_gemm
// GEMMs + attn K/V: m97-style global_load_lds(16B) staging, XOR-swizzled LDS, bf16 MFMA.
// attn: no-max softmax (scores bounded ~|3|), exp2 with pre-scaled bias,
//       double-buffered K/V, fused 268MB bias store.

typedef unsigned short u16;
typedef unsigned int u32;
typedef __attribute__((ext_vector_type(4))) float f32x4;
typedef __attribute__((ext_vector_type(8))) short bf16x8;
typedef __attribute__((ext_vector_type(4))) unsigned short u16x4;

#define MFMA16(a, b, c) __builtin_amdgcn_mfma_f32_16x16x32_bf16(a, b, c, 0, 0, 0)

typedef const __attribute__((address_space(1))) void gvoid;
typedef __attribute__((address_space(3))) void lvoid;
static __device__ __forceinline__ void gll16(const void* g, void* l) {
    __builtin_amdgcn_global_load_lds((gvoid*)g, (lvoid*)l, 16, 0, 0);
}

static __device__ inline u16 f2bf(float f) {
    u32 x = __float_as_uint(f);
    x += 0x7fffu + ((x >> 16) & 1u);   // RNE
    return (u16)(x >> 16);
}
static __device__ inline u32 pk2(float a, float b) {
    return (u32)f2bf(a) | ((u32)f2bf(b) << 16);
}

// ---------------------------------------------------------------------------
// 1) prep: blocks [0,2048) convert X->bf16; [2048,3072) transpose weights to
//    bf16 [n][k]; [3072,3328) build bias table.
// ---------------------------------------------------------------------------
__global__ __launch_bounds__(256) void prep(
    const float* __restrict__ X, const float* __restrict__ Wq,
    const float* __restrict__ Wkv, const float* __restrict__ Wo,
    const float* __restrict__ rel_bias, u16* __restrict__ Xb,
    u16* __restrict__ Wt, float* __restrict__ tbl)
{
    __shared__ u16 T[64 * 72];
    const int bx = blockIdx.x, tid = threadIdx.x;
    if (bx < 2048) {                       // convert X
        int i = (bx * 256 + tid) * 8;
        float4 a = *(const float4*)(X + i);
        float4 b = *(const float4*)(X + i + 4);
        uint4 w = { pk2(a.x, a.y), pk2(a.z, a.w), pk2(b.x, b.y), pk2(b.z, b.w) };
        *(uint4*)(Xb + i) = w;
    } else if (bx < 3072) {                // transpose weights
        int bx2 = bx - 2048;
        int k0 = (bx2 & 15) * 64;
        int n0 = (bx2 >> 4) * 64;
        const float* src; int ld, nb;
        if (n0 < 1024)      { src = Wq;  ld = 1024; nb = n0; }
        else if (n0 < 3072) { src = Wkv; ld = 2048; nb = n0 - 1024; }
        else                { src = Wo;  ld = 1024; nb = n0 - 3072; }
        const int r0 = tid >> 4, c4 = (tid & 15) * 4;
        for (int rr = 0; rr < 4; rr++) {
            int row = rr * 16 + r0;
            float4 f = *(const float4*)(src + (size_t)(k0 + row) * ld + nb + c4);
            T[(c4 + 0) * 72 + row] = f2bf(f.x);
            T[(c4 + 1) * 72 + row] = f2bf(f.y);
            T[(c4 + 2) * 72 + row] = f2bf(f.z);
            T[(c4 + 3) * 72 + row] = f2bf(f.w);
        }
        __syncthreads();
        const int n = tid >> 2, ks0 = (tid & 3) * 16;
        uint4 u0 = *(const uint4*)&T[n * 72 + ks0];
        uint4 u1 = *(const uint4*)&T[n * 72 + ks0 + 8];
        uint4* d = (uint4*)(Wt + (size_t)(n0 + n) * 1024 + k0 + ks0);
        d[0] = u0; d[1] = u1;
    } else {                               // bias table
        int i = (bx - 3072) * 256 + tid;
        int rel = (i & 4095) - 2047;
        int h = i >> 12;
        int ret = -rel;
        int sign = (ret < 0) ? 1 : 0;
        int aret = (ret < 0) ? -ret : ret;
        int bucket;
        if (aret < 8) {
            bucket = aret;
        } else {
            float v = (logf((float)aret * 0.125f + 1e-6f) / logf(16.0f)) * 8.0f;
            int iv = (int)v;               // trunc toward zero, v >= 0 here
            bucket = 8 + (iv < 7 ? iv : 7);
        }
        bucket += sign * 16;
        tbl[i] = rel_bias[h * 32 + bucket];
    }
}

// ---------------------------------------------------------------------------
// 2) QKV GEMM (bf16): Xb[4096,1024] @ Wt[0:3072]^T -> q,k [B,H,2048,64],
//    v TRANSPOSED [B,H,64,2048]. 128x128 tile, BK=64, global_load_lds staging
//    with XOR swizzle (slot = chunk ^ (row&7)), stride 64 (no pad).
// ---------------------------------------------------------------------------
__global__ __launch_bounds__(256) void qkv_gemm(
    const u16* __restrict__ Xb, const u16* __restrict__ Wt,
    u16* __restrict__ qws, u16* __restrict__ kws, u16* __restrict__ vtws)
{
    __shared__ u16 As[128 * 64];
    __shared__ u16 Bs[128 * 64];
    const int tid = threadIdx.x;
    const int n0 = blockIdx.x * 128;
    const int m0 = blockIdx.y * 128;
    const int wid = tid >> 6, lane = tid & 63, c = lane & 15, quad = lane >> 4;
    const int wm = (wid >> 1) * 64, wn = (wid & 1) * 64;
    const f32x4 z = {0.f, 0.f, 0.f, 0.f};
    f32x4 acc[4][4];
    for (int i = 0; i < 4; i++) for (int j = 0; j < 4; j++) acc[i][j] = z;
    const int rsub = lane >> 3;
    const int dchunk = (lane & 7) ^ (rsub & 7);          // swizzled source chunk
    const u16* ag = Xb + (size_t)(m0 + wid * 32 + rsub) * 1024 + dchunk * 8;
    const u16* bg = Wt + (size_t)(n0 + wid * 32 + rsub) * 1024 + dchunk * 8;
    u16* lA = &As[(wid * 32) * 64];
    u16* lB = &Bs[(wid * 32) * 64];
    const int sw = c & 7;

    for (int kk = 0; kk < 1024; kk += 64) {
        for (int i = 0; i < 4; i++)
            gll16(ag + (size_t)i * 8 * 1024 + kk, lA + i * 8 * 64);
        for (int i = 0; i < 4; i++)
            gll16(bg + (size_t)i * 8 * 1024 + kk, lB + i * 8 * 64);
        __syncthreads();
        for (int ks = 0; ks < 2; ks++) {
            const int sl = ((ks * 4 + quad) ^ sw) * 8;
            bf16x8 af[4], bfr[4];
            for (int im = 0; im < 4; im++)
                af[im] = *(const bf16x8*)&As[(wm + im * 16 + c) * 64 + sl];
            for (int jn = 0; jn < 4; jn++)
                bfr[jn] = *(const bf16x8*)&Bs[(wn + jn * 16 + c) * 64 + sl];
            for (int im = 0; im < 4; im++)
                for (int jn = 0; jn < 4; jn++)
                    acc[im][jn] = MFMA16(af[im], bfr[jn], acc[im][jn]);
        }
        __syncthreads();
    }
    for (int im = 0; im < 4; im++) for (int jn = 0; jn < 4; jn++) {
        int gm0 = m0 + wm + im * 16 + quad * 4;
        int gn = n0 + wn + jn * 16 + c;
        if (gn < 2048) {
            u16* dstbase = (gn < 1024) ? qws : kws;
            int nn = gn & 1023;
            int h = nn >> 6, d = nn & 63;
            for (int r = 0; r < 4; r++) {
                int gm = gm0 + r, bb = gm >> 11, l = gm & 2047;
                dstbase[(((size_t)bb * 16 + h) * 2048 + l) * 64 + d] = f2bf(acc[im][jn][r]);
            }
        } else {
            int nn = gn - 2048;
            int h = nn >> 6, d = nn & 63;
            int bb = gm0 >> 11, l = gm0 & 2047;   // 4 consecutive l -> 8B store
            u16x4 pk = { f2bf(acc[im][jn][0]), f2bf(acc[im][jn][1]),
                         f2bf(acc[im][jn][2]), f2bf(acc[im][jn][3]) };
            *(u16x4*)&vtws[(((size_t)bb * 16 + h) * 64 + d) * 2048 + l] = pk;
        }
    }
}

// ---------------------------------------------------------------------------
// 3) Flash attention + fused bias write.
//    Block (qt, bh): 128 queries of one (b,h); 4 waves x 32 queries.
//    K/V staged via global_load_lds (16B) into XOR-swizzled stride-64 LDS,
//    double-buffered, one barrier/iter. Bias window pre-scaled by log2e for
//    exp2-based softmax. Also writes bias[h, q0:q0+128, kt-half] (b selects
//    the j-half) so the 268 MB bias store overlaps attention compute.
// ---------------------------------------------------------------------------
__global__ __launch_bounds__(256, 2) void attn_kernel(
    const u16* __restrict__ qws, const u16* __restrict__ kws,
    const u16* __restrict__ vtws, const float* __restrict__ tbl,
    u16* __restrict__ ows, float* __restrict__ bias_out)
{
    __shared__ u16 QPs[128 * 72];     // Q staging, then per-wave P buffers
    __shared__ u16 Ks[2][64 * 64];    // packed stride 64, XOR-swizzled chunks
    __shared__ u16 Vt[2][64 * 64];
    __shared__ float Bw[2][192];      // bias window, pre-scaled by log2(e)
    const int tid = threadIdx.x;
    const int qt = blockIdx.x, bh = blockIdx.y;
    const int b = bh >> 4, h = bh & 15;
    const u16* qp = qws + (size_t)bh * 2048 * 64;
    const u16* kp = kws + (size_t)bh * 2048 * 64;
    const u16* vp = vtws + (size_t)bh * 64 * 2048;
    const float* tb = tbl + h * 4096;
    const int q0 = qt * 128;
    const int wid = tid >> 6, lane = tid & 63, c = lane & 15, quad = lane >> 4;
    const int qw0 = wid * 32;
    const int sw = c & 7;
    const int rsub = lane >> 3;                  // 0..7
    const int schunk = (lane & 7) ^ rsub;        // swizzled source chunk
    // fused bias-write coords (j-half = b)
    const int birow = tid >> 3, bjj = (tid & 7) * 4;

    // async K/V tile stage: rows wid*16+g*8+rsub, swizzled chunk, to buf
    auto stage = [&](int buf, int k0) {
        for (int g = 0; g < 2; g++) {
            gll16(kp + (size_t)(k0 + wid * 16 + g * 8 + rsub) * 64 + schunk * 8,
                  &Ks[buf][(wid * 16 + g * 8) * 64]);
            gll16(vp + (size_t)(wid * 16 + g * 8 + rsub) * 2048 + k0 + schunk * 8,
                  &Vt[buf][(wid * 16 + g * 8) * 64]);
        }
        if (tid < 192) Bw[buf][tid] = tb[k0 - q0 + 1920 + tid] * 1.44269504f;
    };

    stage(0, 0);
    {   // stage Q tile [128][64] -> QPs (stride 72)
        int row = tid >> 1, c0 = (tid & 1) * 32;
        const uint4* s = (const uint4*)(qp + (size_t)(q0 + row) * 64 + c0);
        uint4 v0 = s[0], v1 = s[1], v2 = s[2], v3 = s[3];
        uint4* d = (uint4*)&QPs[row * 72 + c0];
        d[0] = v0; d[1] = v1; d[2] = v2; d[3] = v3;
    }
    __syncthreads();
    bf16x8 bq[2][2];   // B-frags of Q^T
    for (int nt = 0; nt < 2; nt++)
        for (int ks = 0; ks < 2; ks++)
            bq[nt][ks] = *(const bf16x8*)&QPs[(qw0 + nt * 16 + c) * 72 + ks * 32 + quad * 8];
    __syncthreads();   // all Q reads done -> QPs becomes per-wave P buffers
    u16* Ps = QPs + wid * (32 * 72);

    float lrow[2] = { 0.f, 0.f };
    const f32x4 z = {0.f, 0.f, 0.f, 0.f};
    f32x4 accO[2][4];
    for (int i = 0; i < 2; i++) for (int j = 0; j < 4; j++) accO[i][j] = z;

    for (int kt = 0; kt < 32; kt++) {
        const int cur = kt & 1;
        const int k0 = kt * 64;
        if (kt < 31) stage(cur ^ 1, k0 + 64);   // async prefetch into other buf
        // S^T [64 key x 32 q] per wave
        f32x4 accS[4][2];
        for (int i = 0; i < 4; i++) { accS[i][0] = z; accS[i][1] = z; }
        for (int ks = 0; ks < 2; ks++)
            for (int ktile = 0; ktile < 4; ktile++) {
                bf16x8 ak = *(const bf16x8*)
                    &Ks[cur][(ktile * 16 + c) * 64 + (((ks * 4 + quad) ^ sw)) * 8];
                accS[ktile][0] = MFMA16(ak, bq[0][ks], accS[ktile][0]);
                accS[ktile][1] = MFMA16(ak, bq[1][ks], accS[ktile][1]);
            }
        // p = exp2(s*(0.125*log2e) + bias*log2e); row sums; pack -> Ps
        float rsum[2] = { 0.f, 0.f };
        for (int ktile = 0; ktile < 4; ktile++)
            for (int nt = 0; nt < 2; nt++) {
                const float* bp = &Bw[cur][ktile * 16 + quad * 4 - qw0 - nt * 16 - c + 127];
                float p0 = exp2f(fmaf(accS[ktile][nt][0], 0.180336878f, bp[0]));
                float p1 = exp2f(fmaf(accS[ktile][nt][1], 0.180336878f, bp[1]));
                float p2 = exp2f(fmaf(accS[ktile][nt][2], 0.180336878f, bp[2]));
                float p3 = exp2f(fmaf(accS[ktile][nt][3], 0.180336878f, bp[3]));
                rsum[nt] += (p0 + p1) + (p2 + p3);
                u16x4 pk = { f2bf(p0), f2bf(p1), f2bf(p2), f2bf(p3) };
                *(u16x4*)&Ps[(nt * 16 + c) * 72 + ktile * 16 + quad * 4] = pk;
            }
        lrow[0] += rsum[0]; lrow[1] += rsum[1];
        // P·V
        for (int kb = 0; kb < 2; kb++) {
            bf16x8 bv[4];
            for (int nt = 0; nt < 4; nt++)
                bv[nt] = *(const bf16x8*)
                    &Vt[cur][(nt * 16 + c) * 64 + (((kb * 4 + quad) ^ sw)) * 8];
            for (int mt = 0; mt < 2; mt++) {
                bf16x8 ap = *(const bf16x8*)&Ps[(mt * 16 + c) * 72 + kb * 32 + quad * 8];
                for (int nt = 0; nt < 4; nt++)
                    accO[mt][nt] = MFMA16(ap, bv[nt], accO[mt][nt]);
            }
        }
        // fused bias write: bias[h, q0+i, k0 + b*32 + jj], 128x32 slab
        {
            const int jbase = k0 + b * 32 + bjj;
            const float* tw = tb + (jbase + 2047 - q0);
            float* dstb = bias_out + ((size_t)h * 2048 + q0 + birow) * 2048 + jbase;
            for (int rr = 0; rr < 4; rr++) {
                const float* twp = tw - (birow + rr * 32);
                f32x4 v = { twp[0], twp[1], twp[2], twp[3] };
                __builtin_nontemporal_store(v, (f32x4*)(dstb + (size_t)rr * 32 * 2048));
            }
        }
        // single barrier per iter: drains gll (vmcnt) + LDS, swaps buffers
        __syncthreads();
    }
    for (int nt = 0; nt < 2; nt++) {
        lrow[nt] += __shfl_xor(lrow[nt], 16, 64);
        lrow[nt] += __shfl_xor(lrow[nt], 32, 64);
    }
    for (int mt = 0; mt < 2; mt++)
        for (int r = 0; r < 4; r++) {
            float lq = __shfl(lrow[mt], quad * 4 + r, 64);
            float rl = 1.0f / lq;
            int qg = q0 + qw0 + mt * 16 + quad * 4 + r;
            size_t base = ((size_t)b * 2048 + qg) * 1024 + h * 64;
            for (int nt = 0; nt < 4; nt++)
                ows[base + nt * 16 + c] = f2bf(accO[mt][nt][r] * rl);
        }
}

// ---------------------------------------------------------------------------
// 4) out = O_bf16 [4096,1024] @ Wo^T(bf16) -> fp32, global_load_lds staging.
// ---------------------------------------------------------------------------
__global__ __launch_bounds__(256) void out_gemm(
    const u16* __restrict__ O, const u16* __restrict__ Wot, float* __restrict__ out)
{
    __shared__ u16 As[128 * 64];
    __shared__ u16 Bs[128 * 64];
    const int tid = threadIdx.x;
    const int n0 = blockIdx.x * 128;
    const int m0 = blockIdx.y * 128;
    const int wid = tid >> 6, lane = tid & 63, c = lane & 15, quad = lane >> 4;
    const int wm = (wid >> 1) * 64, wn = (wid & 1) * 64;
    const f32x4 z = {0.f, 0.f, 0.f, 0.f};
    f32x4 acc[4][4];
    for (int i = 0; i < 4; i++) for (int j = 0; j < 4; j++) acc[i][j] = z;
    const int rsub = lane >> 3;
    const int dchunk = (lane & 7) ^ (rsub & 7);
    const u16* ag = O + (size_t)(m0 + wid * 32 + rsub) * 1024 + dchunk * 8;
    const u16* bg = Wot + (size_t)(n0 + wid * 32 + rsub) * 1024 + dchunk * 8;
    u16* lA = &As[(wid * 32) * 64];
    u16* lB = &Bs[(wid * 32) * 64];
    const int sw = c & 7;
    for (int kk = 0; kk < 1024; kk += 64) {
        for (int i = 0; i < 4; i++)
            gll16(ag + (size_t)i * 8 * 1024 + kk, lA + i * 8 * 64);
        for (int i = 0; i < 4; i++)
            gll16(bg + (size_t)i * 8 * 1024 + kk, lB + i * 8 * 64);
        __syncthreads();
        for (int ks = 0; ks < 2; ks++) {
            const int sl = ((ks * 4 + quad) ^ sw) * 8;
            bf16x8 af[4], bfr[4];
            for (int im = 0; im < 4; im++)
                af[im] = *(const bf16x8*)&As[(wm + im * 16 + c) * 64 + sl];
            for (int jn = 0; jn < 4; jn++)
                bfr[jn] = *(const bf16x8*)&Bs[(wn + jn * 16 + c) * 64 + sl];
            for (int im = 0; im < 4; im++)
                for (int jn = 0; jn < 4; jn++)
                    acc[im][jn] = MFMA16(af[im], bfr[jn], acc[im][jn]);
        }
        __syncthreads();
    }
    for (int im = 0; im < 4; im++) for (int jn = 0; jn < 4; jn++) {
        int gm0 = m0 + wm + im * 16 + quad * 4;
        int gn = n0 + wn + jn * 16 + c;
        for (int r = 0; r < 4; r++)
            __builtin_nontemporal_store(acc[im][jn][r], &out[(size_t)(gm0 + r) * 1024 + gn]);
    }
}

// ---------------------------------------------------------------------------
extern "C" void kernel_launch(void* const* d_in, const int* in_sizes, int n_in,
                              void* d_out, int out_size, void* d_ws, size_t ws_size,
                              hipStream_t stream)
{
    (void)in_sizes; (void)n_in; (void)out_size; (void)ws_size;
    const float* query    = (const float*)d_in[0];
    const float* Wq       = (const float*)d_in[1];
    const float* Wkv      = (const float*)d_in[2];
    const float* Wo       = (const float*)d_in[3];
    const float* rel_bias = (const float*)d_in[4];
    float* out = (float*)d_out;

    float* tbl = (float*)d_ws;                         // 16*4096 fp32 = 256 KB
    u16* Xb   = (u16*)((char*)d_ws + 262144);          // [4096,1024] bf16, 8 MB
    u16* Wt   = Xb + 4194304;                          // [4096,1024] bf16, 8 MB
    u16* qws  = Wt + 4194304;                          // [B,H,2048,64] bf16, 8 MB
    u16* kws  = qws + 4194304;                         // 8 MB
    u16* vtws = kws + 4194304;                         // [B,H,64,2048] bf16, 8 MB
    u16* ows  = vtws + 4194304;                        // [B,L,H*64] bf16, 8 MB

    prep<<<3328, 256, 0, stream>>>(query, Wq, Wkv, Wo, rel_bias, Xb, Wt, tbl);
    qkv_gemm<<<dim3(24, 32), 256, 0, stream>>>(Xb, Wt, qws, kws, vtws);
    attn_kernel<<<dim3(16, 32), 256, 0, stream>>>(qws, kws, vtws, tbl, ows,
                                                  out + 4194304);
    out_gemm<<<dim3(8, 32), 256, 0, stream>>>(ows, Wt + (size_t)3072 * 1024, out);
}